// Round 1
// 128.307 us; speedup vs baseline: 1.0072x; 1.0072x over previous
//
#include <hip/hip_runtime.h>
#include <hip/hip_bf16.h>

typedef unsigned short u16x8 __attribute__((ext_vector_type(8)));
typedef __bf16 bf16x8 __attribute__((ext_vector_type(8)));
typedef float f32x4 __attribute__((ext_vector_type(4)));

#define NODE_DIM 128
#define LPAD 136   // +8 u16 pad: 2-way bank alias only (free per m136)

__device__ __forceinline__ unsigned short f2bf(float f) {
  union { float f; unsigned int u; } v; v.f = f;
  unsigned int u = v.u;
  u += 0x7fffu + ((u >> 16) & 1u);   // RNE
  return (unsigned short)(u >> 16);
}
__device__ __forceinline__ float bf2f(unsigned short s) {
  union { unsigned int u; float f; } v; v.u = ((unsigned int)s) << 16;
  return v.f;
}

// W1 (256x64 row-major fp32) -> Wt[j][k] bf16, j,k in [0,128):
//   j<64 : W1[k][j],  j>=64: W1[k+128][j-64]   (k-contiguous)
__global__ void prep_wt(const float* __restrict__ W1, unsigned short* __restrict__ Wt) {
  for (int i = blockIdx.x * blockDim.x + threadIdx.x; i < 128 * 128;
       i += gridDim.x * blockDim.x) {
    int j = i >> 7, k = i & 127;
    float w = (j < 64) ? W1[k * 64 + j] : W1[(k + 128) * 64 + (j - 64)];
    Wt[i] = f2bf(w);
  }
}

// PQ[n][j] = sum_k x[n][k] * Wt[j][k]
// B from LDS (staged once per block, 34.8 KB -> 4 blocks/CU);
// A direct from global, f2bf in regs (R2-proven); 2 x 64-row steps/block.
__global__ __launch_bounds__(256) void gemm_pq(const float* __restrict__ x,
                                               const unsigned short* __restrict__ Wt,
                                               unsigned short* __restrict__ PQ,
                                               int n_nodes) {
  __shared__ unsigned short bs[128][LPAD];
  const int tid = threadIdx.x;

  // Wt bf16 -> bs: 16B chunks, coalesced (8 iters/thread)
  for (int i = tid; i < 128 * 16; i += 256) {
    int j = i >> 4, c = i & 15;
    *(u16x8*)&bs[j][c * 8] = *(const u16x8*)&Wt[j * 128 + c * 8];
  }
  __syncthreads();

  const int wave = tid >> 6, lane = tid & 63;
  const int m = lane & 15, q = lane >> 4;

  #pragma unroll
  for (int step = 0; step < 2; ++step) {
    const int row0 = blockIdx.x * 128 + step * 64 + wave * 16;  // 16 rows/wave
    if (row0 < n_nodes) {
      const int arow = min(row0 + m, n_nodes - 1);  // OOB lanes clamp; stores guarded
      const float* xr = x + (size_t)arow * NODE_DIM;

      // lane's full A share: 8 float4, all issued before first use
      float4 av[4][2];
      #pragma unroll
      for (int kk = 0; kk < 4; kk++) {
        av[kk][0] = *(const float4*)&xr[kk * 32 + q * 8];
        av[kk][1] = *(const float4*)&xr[kk * 32 + q * 8 + 4];
      }

      f32x4 acc[8];
      #pragma unroll
      for (int t = 0; t < 8; t++) acc[t] = f32x4{0.f, 0.f, 0.f, 0.f};

      #pragma unroll
      for (int kk = 0; kk < 4; kk++) {
        // A[m = lane&15][k = kk*32 + q*8 + j]  (layout + this build proven R2)
        union { unsigned short s[8]; u16x8 v; } au;
        au.s[0] = f2bf(av[kk][0].x); au.s[1] = f2bf(av[kk][0].y);
        au.s[2] = f2bf(av[kk][0].z); au.s[3] = f2bf(av[kk][0].w);
        au.s[4] = f2bf(av[kk][1].x); au.s[5] = f2bf(av[kk][1].y);
        au.s[6] = f2bf(av[kk][1].z); au.s[7] = f2bf(av[kk][1].w);
        bf16x8 a = __builtin_bit_cast(bf16x8, au.v);
        #pragma unroll
        for (int t = 0; t < 8; t++) {
          // B[k][n = t*16 + m] from LDS, k-contiguous 16B (proven R1)
          bf16x8 b = __builtin_bit_cast(bf16x8,
              *(const u16x8*)&bs[t * 16 + m][kk * 32 + q * 8]);
          acc[t] = __builtin_amdgcn_mfma_f32_16x16x32_bf16(a, b, acc[t], 0, 0, 0);
        }
      }

      // C/D: col = t*16 + (lane&15), row = q*4 + reg  (proven R1)
      #pragma unroll
      for (int t = 0; t < 8; t++) {
        #pragma unroll
        for (int r = 0; r < 4; r++) {
          int gr = row0 + q * 4 + r;
          if (gr < n_nodes) PQ[(size_t)gr * 128 + t * 16 + m] = f2bf(acc[t][r]);
        }
      }
    }
  }
}

// 8 lanes per edge-PAIR: each 8-lane group handles edges (2g, 2g+1).
// Doubles in-flight gathers per wave; weight loads vectorized to float4
// (16 scalar -> 4 vector VMEM insts); per-edge math identical to R3.
__global__ __launch_bounds__(256) void edge_mlp(const int* __restrict__ ei,
                                                const unsigned short* __restrict__ PQ,
                                                const float* __restrict__ b1,
                                                const float* __restrict__ W2,
                                                const float* __restrict__ b2,
                                                float* __restrict__ out, int E) {
  const int t = blockIdx.x * 256 + threadIdx.x;
  const int g = t >> 3, l = t & 7;
  const int e0 = g * 2;
  if (e0 >= E) return;
  const bool has1 = (e0 + 1) < E;

  // per-lane weight slice (L1-resident, 4 vector loads)
  float b1v[8], w2v[8];
  *(float4*)&b1v[0] = *(const float4*)&b1[l * 8];
  *(float4*)&b1v[4] = *(const float4*)&b1[l * 8 + 4];
  *(float4*)&w2v[0] = *(const float4*)&W2[l * 8];
  *(float4*)&w2v[4] = *(const float4*)&W2[l * 8 + 4];

  // issue all 4 gathers before any use (2x MLP vs 1-edge version)
  const int row0 = ei[e0], col0 = ei[E + e0];
  u16x8 pu0 = *(const u16x8*)&PQ[(size_t)row0 * 128 + l * 8];
  u16x8 qu0 = *(const u16x8*)&PQ[(size_t)col0 * 128 + 64 + l * 8];
  int row1 = row0, col1 = col0;
  if (has1) { row1 = ei[e0 + 1]; col1 = ei[E + e0 + 1]; }
  u16x8 pu1 = *(const u16x8*)&PQ[(size_t)row1 * 128 + l * 8];
  u16x8 qu1 = *(const u16x8*)&PQ[(size_t)col1 * 128 + 64 + l * 8];

  float p0 = 0.f, p1 = 0.f;
  #pragma unroll
  for (int i = 0; i < 8; i++) {
    float h0 = bf2f(pu0[i]) + bf2f(qu0[i]) + b1v[i];
    h0 = fmaxf(h0, 0.f);
    p0 = fmaf(h0, w2v[i], p0);
    float h1 = bf2f(pu1[i]) + bf2f(qu1[i]) + b1v[i];
    h1 = fmaxf(h1, 0.f);
    p1 = fmaf(h1, w2v[i], p1);
  }
  p0 += __shfl_xor(p0, 1); p1 += __shfl_xor(p1, 1);
  p0 += __shfl_xor(p0, 2); p1 += __shfl_xor(p1, 2);
  p0 += __shfl_xor(p0, 4); p1 += __shfl_xor(p1, 4);

  if (l == 0) {
    float s0 = 1.f / (1.f + __expf(-(p0 + b2[0])));
    if (has1) {
      float s1 = 1.f / (1.f + __expf(-(p1 + b2[0])));
      float2 o; o.x = s0; o.y = s1;
      *(float2*)&out[e0] = o;   // e0 even -> 8B aligned
    } else {
      out[e0] = s0;
    }
  }
}

extern "C" void kernel_launch(void* const* d_in, const int* in_sizes, int n_in,
                              void* d_out, int out_size, void* d_ws, size_t ws_size,
                              hipStream_t stream) {
  const float* x  = (const float*)d_in[0];
  const int*   ei = (const int*)d_in[1];
  const float* W1 = (const float*)d_in[2];
  const float* b1 = (const float*)d_in[3];
  const float* W2 = (const float*)d_in[4];
  const float* b2 = (const float*)d_in[5];
  float* out = (float*)d_out;
  const int n_nodes = in_sizes[0] / NODE_DIM;
  const int E = in_sizes[1] / 2;

  // ws: Wt bf16 [128*128] @ 0 (32 KB), PQ bf16 [n_nodes*128] @ 32768 (25.6 MB)
  unsigned short* Wt = (unsigned short*)d_ws;
  unsigned short* PQ = (unsigned short*)((char*)d_ws + 32768);

  prep_wt<<<16, 256, 0, stream>>>(W1, Wt);
  gemm_pq<<<(n_nodes + 127) / 128, 256, 0, stream>>>(x, Wt, PQ, n_nodes);
  const int ngroups = (E + 1) / 2;
  const int egrid = (ngroups * 8 + 255) / 256;
  edge_mlp<<<egrid, 256, 0, stream>>>(ei, PQ, b1, W2, b2, out, E);
}

// Round 2
// 124.828 us; speedup vs baseline: 1.0353x; 1.0279x over previous
//
#include <hip/hip_runtime.h>
#include <hip/hip_bf16.h>

typedef unsigned short u16x8 __attribute__((ext_vector_type(8)));
typedef __bf16 bf16x8 __attribute__((ext_vector_type(8)));
typedef float f32x4 __attribute__((ext_vector_type(4)));
typedef float f32x2 __attribute__((ext_vector_type(2)));

#define NODE_DIM 128
#define LPAD 136   // +8 u16 pad: 2-way bank alias only (free per m136)

__device__ __forceinline__ unsigned short f2bf(float f) {
  union { float f; unsigned int u; } v; v.f = f;
  unsigned int u = v.u;
  u += 0x7fffu + ((u >> 16) & 1u);   // RNE
  return (unsigned short)(u >> 16);
}

// HW fp8 e4m3 (OCP on gfx950) encode/decode
__device__ __forceinline__ unsigned char f2fp8(float f) {
  return (unsigned char)(__builtin_amdgcn_cvt_pk_fp8_f32(f, f, 0, false) & 0xff);
}
__device__ __forceinline__ void fp8x4_to_f32(unsigned int u, float* o) {
  f32x2 lo = __builtin_amdgcn_cvt_pk_f32_fp8(u, false);
  f32x2 hi = __builtin_amdgcn_cvt_pk_f32_fp8(u, true);
  o[0] = lo.x; o[1] = lo.y; o[2] = hi.x; o[3] = hi.y;
}

// W1 (256x64 row-major fp32) -> Wt[j][k] bf16, j,k in [0,128):
//   j<64 : W1[k][j],  j>=64: W1[k+128][j-64]   (k-contiguous)
__global__ void prep_wt(const float* __restrict__ W1, unsigned short* __restrict__ Wt) {
  for (int i = blockIdx.x * blockDim.x + threadIdx.x; i < 128 * 128;
       i += gridDim.x * blockDim.x) {
    int j = i >> 7, k = i & 127;
    float w = (j < 64) ? W1[k * 64 + j] : W1[(k + 128) * 64 + (j - 64)];
    Wt[i] = f2bf(w);
  }
}

// PQ8[n][j] = fp8(sum_k x[n][k] * Wt[j][k] + (j<64 ? b1[j] : 0))
// B from LDS (staged once per block, 34.8 KB -> 4 blocks/CU);
// A direct from global, f2bf in regs (R2-proven); 2 x 64-row steps/block.
__global__ __launch_bounds__(256) void gemm_pq(const float* __restrict__ x,
                                               const unsigned short* __restrict__ Wt,
                                               const float* __restrict__ b1,
                                               unsigned char* __restrict__ PQ8,
                                               int n_nodes) {
  __shared__ unsigned short bs[128][LPAD];
  const int tid = threadIdx.x;

  // Wt bf16 -> bs: 16B chunks, coalesced (8 iters/thread)
  for (int i = tid; i < 128 * 16; i += 256) {
    int j = i >> 4, c = i & 15;
    *(u16x8*)&bs[j][c * 8] = *(const u16x8*)&Wt[j * 128 + c * 8];
  }
  __syncthreads();

  const int wave = tid >> 6, lane = tid & 63;
  const int m = lane & 15, q = lane >> 4;

  // b1 fold for P-half cols (t<4 -> col = t*16+m < 64)
  float b1l[4];
  #pragma unroll
  for (int t = 0; t < 4; t++) b1l[t] = b1[t * 16 + m];

  #pragma unroll
  for (int step = 0; step < 2; ++step) {
    const int row0 = blockIdx.x * 128 + step * 64 + wave * 16;  // 16 rows/wave
    if (row0 < n_nodes) {
      const int arow = min(row0 + m, n_nodes - 1);  // OOB lanes clamp; stores guarded
      const float* xr = x + (size_t)arow * NODE_DIM;

      // lane's full A share: 8 float4, all issued before first use
      float4 av[4][2];
      #pragma unroll
      for (int kk = 0; kk < 4; kk++) {
        av[kk][0] = *(const float4*)&xr[kk * 32 + q * 8];
        av[kk][1] = *(const float4*)&xr[kk * 32 + q * 8 + 4];
      }

      f32x4 acc[8];
      #pragma unroll
      for (int t = 0; t < 8; t++) acc[t] = f32x4{0.f, 0.f, 0.f, 0.f};

      #pragma unroll
      for (int kk = 0; kk < 4; kk++) {
        // A[m = lane&15][k = kk*32 + q*8 + j]  (layout + this build proven R2)
        union { unsigned short s[8]; u16x8 v; } au;
        au.s[0] = f2bf(av[kk][0].x); au.s[1] = f2bf(av[kk][0].y);
        au.s[2] = f2bf(av[kk][0].z); au.s[3] = f2bf(av[kk][0].w);
        au.s[4] = f2bf(av[kk][1].x); au.s[5] = f2bf(av[kk][1].y);
        au.s[6] = f2bf(av[kk][1].z); au.s[7] = f2bf(av[kk][1].w);
        bf16x8 a = __builtin_bit_cast(bf16x8, au.v);
        #pragma unroll
        for (int t = 0; t < 8; t++) {
          // B[k][n = t*16 + m] from LDS, k-contiguous 16B (proven R1)
          bf16x8 b = __builtin_bit_cast(bf16x8,
              *(const u16x8*)&bs[t * 16 + m][kk * 32 + q * 8]);
          acc[t] = __builtin_amdgcn_mfma_f32_16x16x32_bf16(a, b, acc[t], 0, 0, 0);
        }
      }

      // C/D: col = t*16 + (lane&15), row = q*4 + reg  (proven R1)
      #pragma unroll
      for (int t = 0; t < 8; t++) {
        #pragma unroll
        for (int r = 0; r < 4; r++) {
          int gr = row0 + q * 4 + r;
          float v = acc[t][r] + (t < 4 ? b1l[t] : 0.f);
          if (gr < n_nodes) PQ8[(size_t)gr * 128 + t * 16 + m] = f2fp8(v);
        }
      }
    }
  }
}

// 8 lanes per edge-PAIR; PQ is fp8 (64B per edge-half gather, b1 pre-folded).
__global__ __launch_bounds__(256) void edge_mlp(const int* __restrict__ ei,
                                                const unsigned char* __restrict__ PQ8,
                                                const float* __restrict__ W2,
                                                const float* __restrict__ b2,
                                                float* __restrict__ out, int E) {
  const int t = blockIdx.x * 256 + threadIdx.x;
  const int g = t >> 3, l = t & 7;
  const int e0 = g * 2;
  if (e0 >= E) return;
  const bool has1 = (e0 + 1) < E;

  // per-lane W2 slice (L1-resident, 2 vector loads)
  float w2v[8];
  *(float4*)&w2v[0] = *(const float4*)&W2[l * 8];
  *(float4*)&w2v[4] = *(const float4*)&W2[l * 8 + 4];

  // issue all 4 gathers before any use
  const int row0 = ei[e0], col0 = ei[E + e0];
  uint2 pu0 = *(const uint2*)&PQ8[(size_t)row0 * 128 + l * 8];
  uint2 qu0 = *(const uint2*)&PQ8[(size_t)col0 * 128 + 64 + l * 8];
  int row1 = row0, col1 = col0;
  if (has1) { row1 = ei[e0 + 1]; col1 = ei[E + e0 + 1]; }
  uint2 pu1 = *(const uint2*)&PQ8[(size_t)row1 * 128 + l * 8];
  uint2 qu1 = *(const uint2*)&PQ8[(size_t)col1 * 128 + 64 + l * 8];

  float p0v[8], q0v[8], p1v[8], q1v[8];
  fp8x4_to_f32(pu0.x, &p0v[0]); fp8x4_to_f32(pu0.y, &p0v[4]);
  fp8x4_to_f32(qu0.x, &q0v[0]); fp8x4_to_f32(qu0.y, &q0v[4]);
  fp8x4_to_f32(pu1.x, &p1v[0]); fp8x4_to_f32(pu1.y, &p1v[4]);
  fp8x4_to_f32(qu1.x, &q1v[0]); fp8x4_to_f32(qu1.y, &q1v[4]);

  float p0 = 0.f, p1 = 0.f;
  #pragma unroll
  for (int i = 0; i < 8; i++) {
    float h0 = fmaxf(p0v[i] + q0v[i], 0.f);   // b1 folded into P at gemm
    p0 = fmaf(h0, w2v[i], p0);
    float h1 = fmaxf(p1v[i] + q1v[i], 0.f);
    p1 = fmaf(h1, w2v[i], p1);
  }
  p0 += __shfl_xor(p0, 1); p1 += __shfl_xor(p1, 1);
  p0 += __shfl_xor(p0, 2); p1 += __shfl_xor(p1, 2);
  p0 += __shfl_xor(p0, 4); p1 += __shfl_xor(p1, 4);

  if (l == 0) {
    float s0 = 1.f / (1.f + __expf(-(p0 + b2[0])));
    if (has1) {
      float s1 = 1.f / (1.f + __expf(-(p1 + b2[0])));
      float2 o; o.x = s0; o.y = s1;
      *(float2*)&out[e0] = o;   // e0 even -> 8B aligned
    } else {
      out[e0] = s0;
    }
  }
}

extern "C" void kernel_launch(void* const* d_in, const int* in_sizes, int n_in,
                              void* d_out, int out_size, void* d_ws, size_t ws_size,
                              hipStream_t stream) {
  const float* x  = (const float*)d_in[0];
  const int*   ei = (const int*)d_in[1];
  const float* W1 = (const float*)d_in[2];
  const float* b1 = (const float*)d_in[3];
  const float* W2 = (const float*)d_in[4];
  const float* b2 = (const float*)d_in[5];
  float* out = (float*)d_out;
  const int n_nodes = in_sizes[0] / NODE_DIM;
  const int E = in_sizes[1] / 2;

  // ws: Wt bf16 [128*128] @ 0 (32 KB), PQ8 fp8 [n_nodes*128] @ 32768 (12.8 MB)
  unsigned short* Wt = (unsigned short*)d_ws;
  unsigned char* PQ8 = (unsigned char*)d_ws + 32768;

  prep_wt<<<16, 256, 0, stream>>>(W1, Wt);
  gemm_pq<<<(n_nodes + 127) / 128, 256, 0, stream>>>(x, Wt, b1, PQ8, n_nodes);
  const int ngroups = (E + 1) / 2;
  const int egrid = (ngroups * 8 + 255) / 256;
  edge_mlp<<<egrid, 256, 0, stream>>>(ei, PQ8, W2, b2, out, E);
}